// Round 3
// baseline (192.087 us; speedup 1.0000x reference)
//
#include <hip/hip_runtime.h>
#include <hip/hip_fp16.h>

static constexpr int N  = 100000;
static constexpr int E  = 1600000;
static constexpr int B1 = 128;                     // kD1 block size (1 bucket)
static constexpr int BG = 512;                     // kD2/kF block size (4 lanes/node)

static constexpr int BC     = 1024;                // kC block size
static constexpr int NBLKC  = 512;                 // kC grid (2 blocks/CU)
static constexpr int CHUNKC = E / NBLKC;           // 3125 edges per kC block (exact)
static constexpr int PERC   = (CHUNKC + BC - 1) / BC;  // 4
static constexpr int NBUCK  = (N + 127) / 128;     // 782 buckets of 128 nodes
static constexpr int SLAB   = 3072;                // slab cap (mean 2048, +22 sigma)
static constexpr int GCS    = 16;                  // gcur stride (64 B anti-conflict)

// ---- phase C: hist + wave-scan + slab reservation + deg atomics + scatter ---

__global__ __launch_bounds__(BC, 8) void kC_scatter(
        const int* __restrict__ src, const int* __restrict__ dst,
        int* __restrict__ gcur, int* __restrict__ gslab,
        int* __restrict__ deg) {
    __shared__ int lhist[NBUCK];
    __shared__ int lbase[NBUCK];
    __shared__ int gb[NBUCK];
    __shared__ int wsum[16];
    __shared__ int stage[CHUNKC];

    int t = threadIdx.x, blk = blockIdx.x;
    for (int i = t; i < NBUCK; i += BC) lhist[i] = 0;
    __syncthreads();

    int eb = blk * CHUNKC;
    int ds[PERC], ss[PERC];
#pragma unroll
    for (int k = 0; k < PERC; ++k) {
        int idx = k * BC + t;
        if (idx < CHUNKC) {
            ds[k] = dst[eb + idx];
            ss[k] = src[eb + idx];
            atomicAdd(&lhist[ds[k] >> 7], 1);
            atomicAdd(&deg[ds[k]], 1);          // global in-degree (fire&forget)
        }
    }
    __syncthreads();

    // wave-shuffle exclusive scan of lhist[0..NBUCK) (one element per thread)
    int lane = t & 63, wv = t >> 6;
    int val = (t < NBUCK) ? lhist[t] : 0;
    int inc = val;
#pragma unroll
    for (int off = 1; off < 64; off <<= 1) {
        int u = __shfl_up(inc, off, 64);
        if (lane >= off) inc += u;
    }
    if (lane == 63) wsum[wv] = inc;
    __syncthreads();
    if (wv == 0) {
        int wval = (lane < 16) ? wsum[lane] : 0;
        int winc = wval;
#pragma unroll
        for (int off = 1; off < 16; off <<= 1) {
            int u = __shfl_up(winc, off, 64);
            if (lane >= off) winc += u;
        }
        if (lane < 16) wsum[lane] = winc - wval;   // exclusive wave base
    }
    __syncthreads();
    if (t < NBUCK) lbase[t] = wsum[wv] + inc - val;
    __syncthreads();

    // reserve slab ranges; reset lhist as scatter cursor
    if (t < NBUCK) {
        int h = lhist[t];
        if (h > 0) gb[t] = t * SLAB + atomicAdd(&gcur[t * GCS], h);
        lhist[t] = 0;
    }
    __syncthreads();

    // scatter into LDS stage, bucket-major; packed = (dst&127)<<17 | src
#pragma unroll
    for (int k = 0; k < PERC; ++k) {
        int idx = k * BC + t;
        if (idx < CHUNKC) {
            int d = ds[k], b = d >> 7;
            int r = atomicAdd(&lhist[b], 1);
            stage[lbase[b] + r] = ss[k] | ((d & 127) << 17);
        }
    }
    __syncthreads();

    // run-copy write-out: thread t owns bucket t's contiguous run (no search)
    if (t < NBUCK) {
        int len = lhist[t];
        if (len > 0) {
            int s0 = lbase[t];
            int g  = gb[t];
            int cap = (t + 1) * SLAB - g;  // slab overflow guard
            if (cap < 0) cap = 0;
            if (len > cap) len = cap;
            for (int i = 0; i < len; ++i) gslab[g + i] = stage[s0 + i];
        }
    }
}

// ---- phase D1 (diet): deg -> rofs scan + dis + fp16 xpre (no slab pass) -----

__global__ __launch_bounds__(B1) void kD1_scan(
        const int* __restrict__ deg, int* __restrict__ rofs,
        const float4* __restrict__ x4, __half* __restrict__ xpre) {
    __shared__ int wq;
    int t = threadIdx.x, b = blockIdx.x;
    int n = b * 128 + t;
    int dg = (n < N) ? deg[n] : 0;

    // exclusive scan of 128 degrees (2 waves)
    int wv = t >> 6;
    int inc = dg;
#pragma unroll
    for (int off = 1; off < 64; off <<= 1) {
        int u = __shfl_up(inc, off, 64);
        if ((t & 63) >= off) inc += u;
    }
    if (t == 63) wq = inc;
    __syncthreads();
    int ex = inc - dg + ((wv == 1) ? wq : 0);
    int base = b * SLAB;
    rofs[b * 129 + t] = base + ex;
    if (t == 127) rofs[b * 129 + 128] = base + ex + dg;   // base + ne

    // xpre = fp16(dis * x): one thread per node, 32 B store
    if (n < N) {
        float d = rsqrtf((float)(dg + 1));
        float4 u0 = x4[(size_t)n * 4 + 0];
        float4 u1 = x4[(size_t)n * 4 + 1];
        float4 u2 = x4[(size_t)n * 4 + 2];
        float4 u3 = x4[(size_t)n * 4 + 3];
        ushort4 p0, p1, p2, p3;
        p0.x = __half_as_ushort(__float2half(u0.x * d));
        p0.y = __half_as_ushort(__float2half(u0.y * d));
        p0.z = __half_as_ushort(__float2half(u0.z * d));
        p0.w = __half_as_ushort(__float2half(u0.w * d));
        p1.x = __half_as_ushort(__float2half(u1.x * d));
        p1.y = __half_as_ushort(__float2half(u1.y * d));
        p1.z = __half_as_ushort(__float2half(u1.z * d));
        p1.w = __half_as_ushort(__float2half(u1.w * d));
        p2.x = __half_as_ushort(__float2half(u2.x * d));
        p2.y = __half_as_ushort(__float2half(u2.y * d));
        p2.z = __half_as_ushort(__float2half(u2.z * d));
        p2.w = __half_as_ushort(__float2half(u2.w * d));
        p3.x = __half_as_ushort(__float2half(u3.x * d));
        p3.y = __half_as_ushort(__float2half(u3.y * d));
        p3.z = __half_as_ushort(__float2half(u3.z * d));
        p3.w = __half_as_ushort(__float2half(u3.w * d));
        *(ushort4*)(xpre + (size_t)n * 16)      = p0;
        *(ushort4*)(xpre + (size_t)n * 16 + 4)  = p1;
        *(ushort4*)(xpre + (size_t)n * 16 + 8)  = p2;
        *(ushort4*)(xpre + (size_t)n * 16 + 12) = p3;
    }
}

// ---- phase D2: LDS node-sort (persisted) + deep-unroll gather + fused dense -

__global__ __launch_bounds__(BG) void kD2_agg(
        const __half* __restrict__ xpre, int* __restrict__ gslab,
        const int* __restrict__ rofs, const float* __restrict__ W1,
        const float* __restrict__ b1, const float* __restrict__ W2,
        float2* __restrict__ hpre) {
    __shared__ int st1[SLAB];
    __shared__ int cur[128];
    __shared__ int lofs[129];
    __shared__ float acc[128 * 17];
    __shared__ float sW1[512], sb1[32], sW2[64];
    int t = threadIdx.x, b = blockIdx.x;
    sW1[t] = W1[t];                 // BG == 512 threads, 512 weights
    if (t < 32) sb1[t] = b1[t];
    if (t < 64) sW2[t] = W2[t];
    if (t < 128) cur[t] = 0;
    int base = b * SLAB;
    if (t < 129) lofs[t] = rofs[b * 129 + t] - base;
    __syncthreads();

    int ne = lofs[128];
    // scatter into node-major LDS order (src-only payload)
    for (int k = t; k < ne; k += BG) {
        int p = gslab[base + k];
        int lo = p >> 17;
        int r = atomicAdd(&cur[lo], 1);
        st1[lofs[lo] + r] = p & 0x1FFFF;
    }
    __syncthreads();

    // persist sorted src list (own slab, coalesced) so kF needs no re-sort
    int ne4 = ne & ~3;
    for (int k = 4 * t; k < ne4; k += 4 * BG)
        *(int4*)(gslab + base + k) = *(const int4*)(st1 + k);
    for (int k = ne4 + t; k < ne; k += BG)
        gslab[base + k] = st1[k];

    // register gather: 4 lanes/node = 2 feature halves x 2 edge slices,
    // unroll 4 -> trips ~= deg/8, 4 loads in flight per lane
    int h = t & 1, e = (t >> 1) & 1, nl = t >> 2;
    int n = b * 128 + nl;
    float a0 = 0.f, a1 = 0.f, a2 = 0.f, a3 = 0.f,
          a4 = 0.f, a5 = 0.f, a6 = 0.f, a7 = 0.f;
    if (n < N) {
        auto add8 = [&](int4 w) {
            float2 q0 = __half22float2(*(__half2*)&w.x);
            float2 q1 = __half22float2(*(__half2*)&w.y);
            float2 q2 = __half22float2(*(__half2*)&w.z);
            float2 q3 = __half22float2(*(__half2*)&w.w);
            a0 += q0.x; a1 += q0.y; a2 += q1.x; a3 += q1.y;
            a4 += q2.x; a5 += q2.y; a6 += q3.x; a7 += q3.y;
        };
        int rs = lofs[nl], re = lofs[nl + 1];
        if (e == 0)   // self-loop, counted once per feature half
            add8(*(const int4*)(xpre + (size_t)n * 16 + h * 8));
        int k = rs + e;
        for (; k + 6 < re; k += 8) {
            int s0 = st1[k], s1 = st1[k + 2], s2 = st1[k + 4], s3 = st1[k + 6];
            int4 v0 = *(const int4*)(xpre + (size_t)s0 * 16 + h * 8);
            int4 v1 = *(const int4*)(xpre + (size_t)s1 * 16 + h * 8);
            int4 v2 = *(const int4*)(xpre + (size_t)s2 * 16 + h * 8);
            int4 v3 = *(const int4*)(xpre + (size_t)s3 * 16 + h * 8);
            add8(v0); add8(v1); add8(v2); add8(v3);
        }
        for (; k < re; k += 2)
            add8(*(const int4*)(xpre + (size_t)st1[k] * 16 + h * 8));
    }
    // combine the 2 edge slices (lane bit 1)
    a0 += __shfl_xor(a0, 2, 64); a1 += __shfl_xor(a1, 2, 64);
    a2 += __shfl_xor(a2, 2, 64); a3 += __shfl_xor(a3, 2, 64);
    a4 += __shfl_xor(a4, 2, 64); a5 += __shfl_xor(a5, 2, 64);
    a6 += __shfl_xor(a6, 2, 64); a7 += __shfl_xor(a7, 2, 64);
    if (n < N && e == 0) {
        float* row = acc + nl * 17 + h * 8;
        row[0] = a0; row[1] = a1; row[2] = a2; row[3] = a3;
        row[4] = a4; row[5] = a5; row[6] = a6; row[7] = a7;
    }
    __syncthreads();

    // fused dense: 16->32 (ReLU) ->2, pre-scaled by dis[n]
    if (t < 128) {
        int n2 = b * 128 + t;
        if (n2 < N) {
            int deg = lofs[t + 1] - lofs[t];
            float d = rsqrtf((float)(deg + 1));
            const float* row = acc + t * 17;
            float xi[16];
#pragma unroll
            for (int k = 0; k < 16; ++k) xi[k] = row[k] * d;
            float o0 = 0.f, o1 = 0.f;
#pragma unroll
            for (int c = 0; c < 32; ++c) {
                float hh = sb1[c];
#pragma unroll
                for (int k = 0; k < 16; ++k) hh = fmaf(xi[k], sW1[k * 32 + c], hh);
                hh = fmaxf(hh, 0.f);
                o0 = fmaf(hh, sW2[c * 2 + 0], o0);
                o1 = fmaf(hh, sW2[c * 2 + 1], o1);
            }
            hpre[n2] = make_float2(d * o0, d * o1);
        }
    }
}

// ---- phase F: layer-2 gather over pre-sorted list (deep unroll) -------------

__global__ __launch_bounds__(BG) void kF_l2(
        const float2* __restrict__ hpre, const int* __restrict__ gslab,
        const int* __restrict__ rofs, const float* __restrict__ b2,
        float2* __restrict__ out) {
    __shared__ int st1[SLAB];
    __shared__ int lofs[129];
    int t = threadIdx.x, b = blockIdx.x;
    int base = b * SLAB;
    if (t < 129) lofs[t] = rofs[b * 129 + t] - base;
    __syncthreads();

    int ne = lofs[128];
    // bulk copy of pre-sorted src list (vectorized, coalesced)
    int ne4 = ne & ~3;
    for (int k = 4 * t; k < ne4; k += 4 * BG)
        *(int4*)(st1 + k) = *(const int4*)(gslab + base + k);
    for (int k = ne4 + t; k < ne; k += BG)
        st1[k] = gslab[base + k];
    __syncthreads();

    // 4 edge slices per node, unroll 4 -> trips ~= deg/16
    int e = t & 3, nl = t >> 2;
    int n = b * 128 + nl;
    float o0 = 0.f, o1 = 0.f;
    int deg = 0;
    if (n < N) {
        int rs = lofs[nl], re = lofs[nl + 1];
        deg = re - rs;
        if (e == 0) {
            float2 self = hpre[n];
            o0 = self.x; o1 = self.y;
        }
        int k = rs + e;
        for (; k + 12 < re; k += 16) {
            float2 v0 = hpre[st1[k]];
            float2 v1 = hpre[st1[k + 4]];
            float2 v2 = hpre[st1[k + 8]];
            float2 v3 = hpre[st1[k + 12]];
            o0 += (v0.x + v1.x) + (v2.x + v3.x);
            o1 += (v0.y + v1.y) + (v2.y + v3.y);
        }
        for (; k < re; k += 4) {
            float2 v = hpre[st1[k]];
            o0 += v.x; o1 += v.y;
        }
    }
    o0 += __shfl_xor(o0, 1, 64); o1 += __shfl_xor(o1, 1, 64);
    o0 += __shfl_xor(o0, 2, 64); o1 += __shfl_xor(o1, 2, 64);
    if (n < N && e == 0) {
        float d = rsqrtf((float)(deg + 1));
        out[n] = make_float2(fmaf(d, o0, b2[0]), fmaf(d, o1, b2[1]));
    }
}

// ---- launcher ---------------------------------------------------------------

extern "C" void kernel_launch(void* const* d_in, const int* in_sizes, int n_in,
                              void* d_out, int out_size, void* d_ws, size_t ws_size,
                              hipStream_t stream) {
    const float* x  = (const float*)d_in[0];
    const int*   ei = (const int*)d_in[1];
    const float* W1 = (const float*)d_in[2];
    const float* b1 = (const float*)d_in[3];
    const float* W2 = (const float*)d_in[4];
    const float* b2 = (const float*)d_in[5];

    const int* src = ei;
    const int* dst = ei + E;

    // workspace layout (4-byte words; xpre offset stays 16 B aligned)
    int*    gslab = (int*)d_ws;                        // NBUCK*SLAB = 2,402,304
    int*    rofs  = gslab + (size_t)NBUCK * SLAB;      // 782*129 -> pad 100,880
    int*    gcur  = rofs + 100880;                     // 782*16 = 12,512
    int*    deg   = gcur + 12512;                      // 100,000 (zeroed with gcur)
    float*  hpre  = (float*)(deg + 100000);            // 2N
    __half* xpre  = (__half*)(hpre + 2 * (size_t)N);   // 16N halfs (3.2 MB)

    hipMemsetAsync(gcur, 0, (NBUCK * GCS + N) * sizeof(int), stream);
    kC_scatter<<<NBLKC, BC, 0, stream>>>(src, dst, gcur, gslab, deg);
    kD1_scan<<<NBUCK, B1, 0, stream>>>(deg, rofs, (const float4*)x, xpre);
    kD2_agg<<<NBUCK, BG, 0, stream>>>(xpre, gslab, rofs, W1, b1, W2, (float2*)hpre);
    kF_l2<<<NBUCK, BG, 0, stream>>>((const float2*)hpre, gslab, rofs, b2,
                                    (float2*)d_out);
}

// Round 4
// 128.029 us; speedup vs baseline: 1.5003x; 1.5003x over previous
//
#include <hip/hip_runtime.h>
#include <hip/hip_fp16.h>

static constexpr int N  = 100000;
static constexpr int E  = 1600000;
static constexpr int B  = 256;                     // kD1 block size
static constexpr int BG = 512;                     // kD2/kF block size (4 lanes/node)

static constexpr int BC     = 1024;                // kC block size
static constexpr int NBLKC  = 256;                 // kC grid (1 block/CU)
static constexpr int CHUNKC = E / NBLKC;           // 6250 edges per kC block (exact)
static constexpr int CH2    = CHUNKC / 2;          // 3125 int2 edge pairs
static constexpr int PER2   = (CH2 + BC - 1) / BC; // 4
static constexpr int NBUCK  = (N + 127) / 128;     // 782 buckets of 128 nodes
static constexpr int SLAB   = 3072;                // slab cap (mean 2048, +22 sigma)
static constexpr int GCS    = 16;                  // gcur stride (64 B anti-conflict)

// ---- phase C: hist + slab reservation + direct global scatter ---------------
// (no scan, no LDS stage, no run-copy: r=atomicAdd(cur[b]) -> gslab[gb[b]+r])

__global__ __launch_bounds__(BC) void kC_scatter(
        const int2* __restrict__ src2, const int2* __restrict__ dst2,
        int* __restrict__ gcur, int* __restrict__ gslab) {
    __shared__ int lhist[NBUCK];
    __shared__ int gb[NBUCK];

    int t = threadIdx.x, blk = blockIdx.x;
    for (int i = t; i < NBUCK; i += BC) lhist[i] = 0;
    __syncthreads();

    int eb2 = blk * CH2;
    int2 dsv[PER2], ssv[PER2];
#pragma unroll
    for (int k = 0; k < PER2; ++k) {
        int idx = k * BC + t;
        if (idx < CH2) {
            dsv[k] = dst2[eb2 + idx];
            ssv[k] = src2[eb2 + idx];
            atomicAdd(&lhist[dsv[k].x >> 7], 1);
            atomicAdd(&lhist[dsv[k].y >> 7], 1);
        }
    }
    __syncthreads();

    // reserve slab ranges; reset lhist as scatter cursor
    if (t < NBUCK) {
        int h = lhist[t];
        if (h > 0) gb[t] = t * SLAB + atomicAdd(&gcur[t * GCS], h);
        lhist[t] = 0;
    }
    __syncthreads();

    // direct scatter; packed = (dst&127)<<17 | src, per-element overflow guard
#pragma unroll
    for (int k = 0; k < PER2; ++k) {
        int idx = k * BC + t;
        if (idx < CH2) {
            {
                int d = dsv[k].x, b = d >> 7;
                int r = atomicAdd(&lhist[b], 1);
                int g = gb[b] + r;
                if (g < (b + 1) * SLAB)
                    gslab[g] = ssv[k].x | ((d & 127) << 17);
            }
            {
                int d = dsv[k].y, b = d >> 7;
                int r = atomicAdd(&lhist[b], 1);
                int g = gb[b] + r;
                if (g < (b + 1) * SLAB)
                    gslab[g] = ssv[k].y | ((d & 127) << 17);
            }
        }
    }
}

// ---- phase D1: per-bucket degree hist -> rofs + fp16 xpre -------------------

__global__ void kD1_deg(const int* __restrict__ gcur, const int* __restrict__ gslab,
                        int* __restrict__ rofs, const float4* __restrict__ x4,
                        __half* __restrict__ xpre) {
    __shared__ int c[128];
    __shared__ int wq[2];
    int t = threadIdx.x, b = blockIdx.x;
    if (t < 128) c[t] = 0;
    __syncthreads();

    int ne = min(gcur[b * GCS], SLAB);
    int base = b * SLAB;                       // multiple of 4 -> int4 aligned
    int ne4 = ne & ~3;
    for (int k = 4 * t; k < ne4; k += 4 * B) {
        int4 p4 = *(const int4*)(gslab + base + k);
        atomicAdd(&c[p4.x >> 17], 1);
        atomicAdd(&c[p4.y >> 17], 1);
        atomicAdd(&c[p4.z >> 17], 1);
        atomicAdd(&c[p4.w >> 17], 1);
    }
    if (t < ne - ne4) atomicAdd(&c[gslab[base + ne4 + t] >> 17], 1);
    __syncthreads();

    // exclusive scan of c[0..128) via 2 wave scans
    int lane = t & 63, wv = t >> 6;
    int val = (t < 128) ? c[t] : 0;
    int inc = val;
#pragma unroll
    for (int off = 1; off < 64; off <<= 1) {
        int u = __shfl_up(inc, off, 64);
        if (lane >= off) inc += u;
    }
    if (t == 63) wq[0] = inc;
    __syncthreads();
    if (t < 128) rofs[b * 129 + t] = base + inc - val + ((wv == 1) ? wq[0] : 0);
    if (t == 128) rofs[b * 129 + 128] = base + ne;

    // xpre = fp16(dis * x): 2 lanes/node, 8 halfs each
    int n = b * 128 + (t >> 1), h = t & 1;
    if (n < N) {
        float d = rsqrtf((float)(c[t >> 1] + 1));
        float4 u0 = x4[(size_t)n * 4 + h * 2];
        float4 u1 = x4[(size_t)n * 4 + h * 2 + 1];
        ushort4 p0, p1;
        p0.x = __half_as_ushort(__float2half(u0.x * d));
        p0.y = __half_as_ushort(__float2half(u0.y * d));
        p0.z = __half_as_ushort(__float2half(u0.z * d));
        p0.w = __half_as_ushort(__float2half(u0.w * d));
        p1.x = __half_as_ushort(__float2half(u1.x * d));
        p1.y = __half_as_ushort(__float2half(u1.y * d));
        p1.z = __half_as_ushort(__float2half(u1.z * d));
        p1.w = __half_as_ushort(__float2half(u1.w * d));
        *(ushort4*)(xpre + (size_t)n * 16 + h * 8)     = p0;
        *(ushort4*)(xpre + (size_t)n * 16 + h * 8 + 4) = p1;
    }
}

// ---- phase D2: LDS node-sort (persisted) + deep-unroll gather + fused dense -

__global__ __launch_bounds__(BG) void kD2_agg(
        const __half* __restrict__ xpre, int* __restrict__ gslab,
        const int* __restrict__ rofs, const float* __restrict__ W1,
        const float* __restrict__ b1, const float* __restrict__ W2,
        float2* __restrict__ hpre) {
    __shared__ int st1[SLAB];
    __shared__ int cur[128];
    __shared__ int lofs[129];
    __shared__ float acc[128 * 17];
    __shared__ float sW1[512], sb1[32], sW2[64];
    int t = threadIdx.x, b = blockIdx.x;
    sW1[t] = W1[t];                 // BG == 512 threads, 512 weights
    if (t < 32) sb1[t] = b1[t];
    if (t < 64) sW2[t] = W2[t];
    if (t < 128) cur[t] = 0;
    int base = b * SLAB;
    if (t < 129) lofs[t] = rofs[b * 129 + t] - base;
    __syncthreads();

    int ne = lofs[128];
    // scatter into node-major LDS order (src-only payload)
    for (int k = t; k < ne; k += BG) {
        int p = gslab[base + k];
        int lo = p >> 17;
        int r = atomicAdd(&cur[lo], 1);
        st1[lofs[lo] + r] = p & 0x1FFFF;
    }
    __syncthreads();

    // persist sorted src list (own slab, coalesced) so kF needs no re-sort
    int ne4 = ne & ~3;
    for (int k = 4 * t; k < ne4; k += 4 * BG)
        *(int4*)(gslab + base + k) = *(const int4*)(st1 + k);
    for (int k = ne4 + t; k < ne; k += BG)
        gslab[base + k] = st1[k];

    // register gather: 4 lanes/node = 2 feature halves x 2 edge slices,
    // unroll 4 -> trips ~= deg/8, 4 loads in flight per lane
    int h = t & 1, e = (t >> 1) & 1, nl = t >> 2;
    int n = b * 128 + nl;
    float a0 = 0.f, a1 = 0.f, a2 = 0.f, a3 = 0.f,
          a4 = 0.f, a5 = 0.f, a6 = 0.f, a7 = 0.f;
    if (n < N) {
        auto add8 = [&](int4 w) {
            float2 q0 = __half22float2(*(__half2*)&w.x);
            float2 q1 = __half22float2(*(__half2*)&w.y);
            float2 q2 = __half22float2(*(__half2*)&w.z);
            float2 q3 = __half22float2(*(__half2*)&w.w);
            a0 += q0.x; a1 += q0.y; a2 += q1.x; a3 += q1.y;
            a4 += q2.x; a5 += q2.y; a6 += q3.x; a7 += q3.y;
        };
        int rs = lofs[nl], re = lofs[nl + 1];
        if (e == 0)   // self-loop, counted once per feature half
            add8(*(const int4*)(xpre + (size_t)n * 16 + h * 8));
        int k = rs + e;
        for (; k + 6 < re; k += 8) {
            int s0 = st1[k], s1 = st1[k + 2], s2 = st1[k + 4], s3 = st1[k + 6];
            int4 v0 = *(const int4*)(xpre + (size_t)s0 * 16 + h * 8);
            int4 v1 = *(const int4*)(xpre + (size_t)s1 * 16 + h * 8);
            int4 v2 = *(const int4*)(xpre + (size_t)s2 * 16 + h * 8);
            int4 v3 = *(const int4*)(xpre + (size_t)s3 * 16 + h * 8);
            add8(v0); add8(v1); add8(v2); add8(v3);
        }
        for (; k < re; k += 2)
            add8(*(const int4*)(xpre + (size_t)st1[k] * 16 + h * 8));
    }
    // combine the 2 edge slices (lane bit 1)
    a0 += __shfl_xor(a0, 2, 64); a1 += __shfl_xor(a1, 2, 64);
    a2 += __shfl_xor(a2, 2, 64); a3 += __shfl_xor(a3, 2, 64);
    a4 += __shfl_xor(a4, 2, 64); a5 += __shfl_xor(a5, 2, 64);
    a6 += __shfl_xor(a6, 2, 64); a7 += __shfl_xor(a7, 2, 64);
    if (n < N && e == 0) {
        float* row = acc + nl * 17 + h * 8;
        row[0] = a0; row[1] = a1; row[2] = a2; row[3] = a3;
        row[4] = a4; row[5] = a5; row[6] = a6; row[7] = a7;
    }
    __syncthreads();

    // fused dense: 16->32 (ReLU) ->2, pre-scaled by dis[n]
    if (t < 128) {
        int n2 = b * 128 + t;
        if (n2 < N) {
            int deg = lofs[t + 1] - lofs[t];
            float d = rsqrtf((float)(deg + 1));
            const float* row = acc + t * 17;
            float xi[16];
#pragma unroll
            for (int k = 0; k < 16; ++k) xi[k] = row[k] * d;
            float o0 = 0.f, o1 = 0.f;
#pragma unroll
            for (int c = 0; c < 32; ++c) {
                float hh = sb1[c];
#pragma unroll
                for (int k = 0; k < 16; ++k) hh = fmaf(xi[k], sW1[k * 32 + c], hh);
                hh = fmaxf(hh, 0.f);
                o0 = fmaf(hh, sW2[c * 2 + 0], o0);
                o1 = fmaf(hh, sW2[c * 2 + 1], o1);
            }
            hpre[n2] = make_float2(d * o0, d * o1);
        }
    }
}

// ---- phase F: layer-2 gather over pre-sorted list (deep unroll) -------------

__global__ __launch_bounds__(BG) void kF_l2(
        const float2* __restrict__ hpre, const int* __restrict__ gslab,
        const int* __restrict__ rofs, const float* __restrict__ b2,
        float2* __restrict__ out) {
    __shared__ int st1[SLAB];
    __shared__ int lofs[129];
    int t = threadIdx.x, b = blockIdx.x;
    int base = b * SLAB;
    if (t < 129) lofs[t] = rofs[b * 129 + t] - base;
    __syncthreads();

    int ne = lofs[128];
    // bulk copy of pre-sorted src list (vectorized, coalesced)
    int ne4 = ne & ~3;
    for (int k = 4 * t; k < ne4; k += 4 * BG)
        *(int4*)(st1 + k) = *(const int4*)(gslab + base + k);
    for (int k = ne4 + t; k < ne; k += BG)
        st1[k] = gslab[base + k];
    __syncthreads();

    // 4 edge slices per node, unroll 4 -> trips ~= deg/16
    int e = t & 3, nl = t >> 2;
    int n = b * 128 + nl;
    float o0 = 0.f, o1 = 0.f;
    int deg = 0;
    if (n < N) {
        int rs = lofs[nl], re = lofs[nl + 1];
        deg = re - rs;
        if (e == 0) {
            float2 self = hpre[n];
            o0 = self.x; o1 = self.y;
        }
        int k = rs + e;
        for (; k + 12 < re; k += 16) {
            float2 v0 = hpre[st1[k]];
            float2 v1 = hpre[st1[k + 4]];
            float2 v2 = hpre[st1[k + 8]];
            float2 v3 = hpre[st1[k + 12]];
            o0 += (v0.x + v1.x) + (v2.x + v3.x);
            o1 += (v0.y + v1.y) + (v2.y + v3.y);
        }
        for (; k < re; k += 4) {
            float2 v = hpre[st1[k]];
            o0 += v.x; o1 += v.y;
        }
    }
    o0 += __shfl_xor(o0, 1, 64); o1 += __shfl_xor(o1, 1, 64);
    o0 += __shfl_xor(o0, 2, 64); o1 += __shfl_xor(o1, 2, 64);
    if (n < N && e == 0) {
        float d = rsqrtf((float)(deg + 1));
        out[n] = make_float2(fmaf(d, o0, b2[0]), fmaf(d, o1, b2[1]));
    }
}

// ---- launcher ---------------------------------------------------------------

extern "C" void kernel_launch(void* const* d_in, const int* in_sizes, int n_in,
                              void* d_out, int out_size, void* d_ws, size_t ws_size,
                              hipStream_t stream) {
    const float* x  = (const float*)d_in[0];
    const int*   ei = (const int*)d_in[1];
    const float* W1 = (const float*)d_in[2];
    const float* b1 = (const float*)d_in[3];
    const float* W2 = (const float*)d_in[4];
    const float* b2 = (const float*)d_in[5];

    const int2* src2 = (const int2*)ei;            // E*4 B base, 8B-aligned
    const int2* dst2 = (const int2*)(ei + E);      // +6.4 MB, 8B-aligned

    // workspace layout (4-byte words; xpre offset stays 16 B aligned)
    int*    gslab = (int*)d_ws;                        // NBUCK*SLAB = 2,402,304
    int*    rofs  = gslab + (size_t)NBUCK * SLAB;      // 782*129 -> pad 100,880
    int*    gcur  = rofs + 100880;                     // 782*16 = 12,512
    float*  hpre  = (float*)(gcur + 12512);            // 2N
    __half* xpre  = (__half*)(hpre + 2 * (size_t)N);   // 16N halfs (3.2 MB)

    hipMemsetAsync(gcur, 0, NBUCK * GCS * sizeof(int), stream);
    kC_scatter<<<NBLKC, BC, 0, stream>>>(src2, dst2, gcur, gslab);
    kD1_deg<<<NBUCK, B, 0, stream>>>(gcur, gslab, rofs, (const float4*)x, xpre);
    kD2_agg<<<NBUCK, BG, 0, stream>>>(xpre, gslab, rofs, W1, b1, W2, (float2*)hpre);
    kF_l2<<<NBUCK, BG, 0, stream>>>((const float2*)hpre, gslab, rofs, b2,
                                    (float2*)d_out);
}